// Round 1
// baseline (1058.167 us; speedup 1.0000x reference)
//
#include <hip/hip_runtime.h>
#include <cstddef>

#define IN_IDX_C  128011
#define OUT_IDX_C 128012
#define PAD_ID_C  128001
#define IGNORE_C  (-100)

// ---------------------------------------------------------------------------
// k1_setup: one block. Builds per-row placeholder tables:
//   shiftA[b]   : left-pad shift for row b  (M - merged_row_total)
//   rowOff[b]   : offset into flat per-row placeholder list (phS/phLen)
//   phS/phLen   : placeholder source column + expanded length, row-major order
//   inRowA/inCol0[p]  : batch row + merged start column of global in-ph p
//   outRowA/outCol0[p]: same for out placeholders
// Global placeholder ordinal = row-major over (b,s), matching jnp.nonzero.
// ---------------------------------------------------------------------------
__global__ void k1_setup(
    const int* __restrict__ ids, const int* __restrict__ in_starts,
    const int* __restrict__ out_starts, const int* __restrict__ pM,
    int BM, int BS, int inRows, int outRows, int nIn, int nOut,
    int* __restrict__ shiftA, int* __restrict__ rowOff,
    int* __restrict__ phS, int* __restrict__ phLen,
    int* __restrict__ inRowA, int* __restrict__ inCol0,
    int* __restrict__ outRowA, int* __restrict__ outCol0)
{
    const int M = pM[0];
    const int B = BM / M;
    const int S = BS / B;
    __shared__ int cin[1024], cou[1024], oin[1024], oou[1024];
    const int tid = threadIdx.x;

    // phase 1: per-row placeholder counts
    for (int b = tid; b < B; b += blockDim.x) {
        int ci = 0, co = 0;
        const int* row = ids + (size_t)b * S;
        for (int s = 0; s < S; ++s) {
            int v = row[s];
            ci += (v == IN_IDX_C);
            co += (v == OUT_IDX_C);
        }
        cin[b] = ci; cou[b] = co;
    }
    __syncthreads();
    // phase 2: prefix offsets (global ordinals)
    if (tid == 0) {
        int oi = 0, oo = 0, op = 0;
        for (int b = 0; b < B; ++b) {
            oin[b] = oi; oou[b] = oo; rowOff[b] = op;
            op += cin[b] + cou[b];
            oi += cin[b]; oo += cou[b];
        }
        rowOff[B] = op;
    }
    __syncthreads();
    // phase 3: per-row tables
    for (int b = tid; b < B; b += blockDim.x) {
        const int* row = ids + (size_t)b * S;
        // pass A: merged row total -> shift
        int pin = oin[b], pou = oou[b];
        int total = 0;
        for (int s = 0; s < S; ++s) {
            int v = row[s];
            if (v == IN_IDX_C) {
                int st = in_starts[pin];
                int en = (pin + 1 < nIn) ? in_starts[pin + 1] : inRows;
                total += en - st; ++pin;
            } else if (v == OUT_IDX_C) {
                int st = out_starts[pou];
                int en = (pou + 1 < nOut) ? out_starts[pou + 1] : outRows;
                total += en - st; ++pou;
            } else {
                total += 1;
            }
        }
        const int shift = M - total;
        shiftA[b] = shift;
        // pass B: fill tables, walking merged column cursor
        pin = oin[b]; pou = oou[b];
        int j = rowOff[b];
        int cum = shift;
        for (int s = 0; s < S; ++s) {
            int v = row[s];
            if (v == IN_IDX_C) {
                int st = in_starts[pin];
                int en = (pin + 1 < nIn) ? in_starts[pin + 1] : inRows;
                int len = en - st;
                phS[j] = s; phLen[j] = len; ++j;
                inRowA[pin] = b; inCol0[pin] = cum;
                cum += len; ++pin;
            } else if (v == OUT_IDX_C) {
                int st = out_starts[pou];
                int en = (pou + 1 < nOut) ? out_starts[pou + 1] : outRows;
                int len = en - st;
                phS[j] = s; phLen[j] = len; ++j;
                outRowA[pou] = b; outCol0[pou] = cum;
                cum += len; ++pou;
            } else {
                cum += 1;
            }
        }
    }
}

// ---------------------------------------------------------------------------
// k2_text: one thread per (b,s) source token; text tokens compute their merged
// column and write map + metadata.
// ---------------------------------------------------------------------------
__global__ void k2_text(
    const int* __restrict__ ids, const int* __restrict__ attm,
    const int* __restrict__ labels, const int* __restrict__ pM,
    int BM, int BS,
    const int* __restrict__ shiftA, const int* __restrict__ rowOff,
    const int* __restrict__ phS, const int* __restrict__ phLen,
    int* __restrict__ map, float* __restrict__ out, int D)
{
    int i = blockIdx.x * blockDim.x + threadIdx.x;
    if (i >= BS) return;
    const int M = pM[0];
    const int B = BM / M;
    const int S = BS / B;
    const int b = i / S, s = i - b * S;
    const int v = ids[i];
    if (v == IN_IDX_C || v == OUT_IDX_C) return;
    int col = shiftA[b] + s;
    const int j1 = rowOff[b + 1];
    for (int j = rowOff[b]; j < j1; ++j) {   // placeholders sorted by s
        if (phS[j] < s) col += phLen[j] - 1; else break;
    }
    const size_t idx = (size_t)b * M + col;
    map[idx] = s;                            // text: encode source column
    float* meta = out + (size_t)BM * D;
    meta[idx]                    = (float)attm[i];   // attention
    meta[(size_t)BM     + idx]   = (float)labels[i]; // labels
    /* position_ids written by k3 */
    meta[(size_t)BM * 3 + idx]   = (float)v;         // input_ids
    meta[(size_t)BM * 4 + idx]   = 0.f;              // in_fill
    meta[(size_t)BM * 5 + idx]   = 0.f;              // in_discrete
    meta[(size_t)BM * 6 + idx]   = 0.f;              // out_fill
}

// ---------------------------------------------------------------------------
// k2_audio: one thread per audio embedding row (in rows then out rows).
// ---------------------------------------------------------------------------
__global__ void k2_audio(
    const int* __restrict__ in_starts, const int* __restrict__ out_starts,
    const int* __restrict__ pM, int BM, int BS, int inRows, int outRows,
    int nIn, int nOut,
    const int* __restrict__ inRowA, const int* __restrict__ inCol0,
    const int* __restrict__ outRowA, const int* __restrict__ outCol0,
    int* __restrict__ map, float* __restrict__ out, int D)
{
    int r = blockIdx.x * blockDim.x + threadIdx.x;
    if (r >= inRows + outRows) return;
    const int M = pM[0];
    const int B = BM / M;
    const int S = BS / B;
    int b, col, enc, iidv, infl, outfl;
    if (r < inRows) {
        int lo = 0, hi = nIn - 1;                 // last p with starts[p] <= r
        while (lo < hi) { int mid = (lo + hi + 1) >> 1;
                          if (in_starts[mid] <= r) lo = mid; else hi = mid - 1; }
        b = inRowA[lo]; col = inCol0[lo] + (r - in_starts[lo]);
        enc = S + r; iidv = IN_IDX_C; infl = 1; outfl = 0;
    } else {
        int r2 = r - inRows;
        int lo = 0, hi = nOut - 1;
        while (lo < hi) { int mid = (lo + hi + 1) >> 1;
                          if (out_starts[mid] <= r2) lo = mid; else hi = mid - 1; }
        b = outRowA[lo]; col = outCol0[lo] + (r2 - out_starts[lo]);
        enc = S + inRows + r2; iidv = OUT_IDX_C; infl = 0; outfl = 1;
    }
    const size_t idx = (size_t)b * M + col;
    map[idx] = enc;
    float* meta = out + (size_t)BM * D;
    meta[idx]                  = 1.f;                  // attention (|= fill)
    meta[(size_t)BM     + idx] = (float)IGNORE_C;      // labels
    meta[(size_t)BM * 3 + idx] = (float)iidv;          // input_ids
    meta[(size_t)BM * 4 + idx] = (float)infl;          // in_fill
    meta[(size_t)BM * 5 + idx] = (float)infl;          // in_discrete
    meta[(size_t)BM * 6 + idx] = (float)outfl;         // out_fill
}

// ---------------------------------------------------------------------------
// k2_pad: one thread per merged column; only the left-pad region writes.
// ---------------------------------------------------------------------------
__global__ void k2_pad(
    const int* __restrict__ pM, int BM,
    const int* __restrict__ shiftA,
    int* __restrict__ map, float* __restrict__ out, int D)
{
    int i = blockIdx.x * blockDim.x + threadIdx.x;
    if (i >= BM) return;
    const int M = pM[0];
    const int b = i / M, m = i - b * M;
    if (m >= shiftA[b]) return;
    map[i] = -1;
    float* meta = out + (size_t)BM * D;
    meta[i]                  = 0.f;                 // attention
    meta[(size_t)BM     + i] = (float)IGNORE_C;     // labels
    meta[(size_t)BM * 3 + i] = (float)PAD_ID_C;     // input_ids
    meta[(size_t)BM * 4 + i] = 0.f;
    meta[(size_t)BM * 5 + i] = 0.f;
    meta[(size_t)BM * 6 + i] = 0.f;
}

// ---------------------------------------------------------------------------
// k3_pos: per-row inclusive scan of attention -> position_ids.
// position = cumsum(att)-1, except att==0 -> 1.
// ---------------------------------------------------------------------------
__global__ void k3_pos(const int* __restrict__ pM, int BM,
                       float* __restrict__ out, int D)
{
    const int M = pM[0];
    const int B = BM / M;
    const float* att = out + (size_t)BM * D;
    float* pos = out + (size_t)BM * D + (size_t)BM * 2;
    __shared__ int sdata[256];
    __shared__ int carry;
    const int tid = threadIdx.x;
    for (int b = blockIdx.x; b < B; b += gridDim.x) {
        if (tid == 0) carry = 0;
        __syncthreads();
        for (int base = 0; base < M; base += blockDim.x) {
            const int m = base + tid;
            const int a = (m < M) ? (int)att[(size_t)b * M + m] : 0;
            int val = a;
            sdata[tid] = val;
            __syncthreads();
            for (int off = 1; off < blockDim.x; off <<= 1) {
                int t = (tid >= off) ? sdata[tid - off] : 0;
                __syncthreads();
                val += t;
                sdata[tid] = val;
                __syncthreads();
            }
            const int incl = val + carry;   // carry stable here
            if (m < M)
                pos[(size_t)b * M + m] = (a == 0) ? 1.f : (float)(incl - 1);
            __syncthreads();
            if (tid == blockDim.x - 1) carry = incl;
            __syncthreads();
        }
        __syncthreads();
    }
}

// ---------------------------------------------------------------------------
// k4_copy: one block per merged column; float4 gather-copy of D floats.
// This carries ~536 MB of the ~540 MB total traffic.
// ---------------------------------------------------------------------------
__global__ void k4_copy(
    const float* __restrict__ audio_in, const float* __restrict__ audio_out,
    const float* __restrict__ inputs_embeds, const int* __restrict__ pM,
    int BM, int BS, int inRows, int D,
    const int* __restrict__ map, float* __restrict__ out)
{
    const int bm = blockIdx.x;
    const int v = map[bm];
    float4* dst = (float4*)(out + (size_t)bm * D);
    const int nq = D >> 2;
    if (v < 0) {
        const float4 z = make_float4(0.f, 0.f, 0.f, 0.f);
        for (int i = threadIdx.x; i < nq; i += blockDim.x) dst[i] = z;
        return;
    }
    const int M = pM[0];
    const int B = BM / M;
    const int S = BS / B;
    const float* src;
    if (v < S) {
        const int b = bm / M;
        src = inputs_embeds + ((size_t)b * S + v) * (size_t)D;
    } else if (v < S + inRows) {
        src = audio_in + (size_t)(v - S) * D;
    } else {
        src = audio_out + (size_t)(v - S - inRows) * D;
    }
    const float4* s4 = (const float4*)src;
    for (int i = threadIdx.x; i < nq; i += blockDim.x) dst[i] = s4[i];
}

// ---------------------------------------------------------------------------
extern "C" void kernel_launch(void* const* d_in, const int* in_sizes, int n_inputs,
                              void* d_out, int out_size, void* d_ws, size_t ws_size,
                              hipStream_t stream) {
    (void)n_inputs; (void)ws_size;
    const float* audio_in      = (const float*)d_in[0];
    const float* audio_out     = (const float*)d_in[1];
    const float* inputs_embeds = (const float*)d_in[2];
    const int* in_starts  = (const int*)d_in[3];
    const int* out_starts = (const int*)d_in[4];
    const int* ids        = (const int*)d_in[5];
    const int* attm       = (const int*)d_in[6];
    const int* labels     = (const int*)d_in[7];
    const int* pM         = (const int*)d_in[8];   // max_token_num (device scalar)

    const int nIn     = in_sizes[3];
    const int nOut    = in_sizes[4];
    const int BS      = in_sizes[5];               // B*S
    const int D       = in_sizes[2] / BS;          // embed dim
    const int inRows  = in_sizes[0] / D;
    const int outRows = in_sizes[1] / D;
    const int BM      = out_size / (D + 7);        // B*M (embedding + 7 metas)

    // workspace layout (ints)
    int* wsI     = (int*)d_ws;
    int* map     = wsI;                // [BM]
    int* shiftA  = map + BM;           // [<=4096]
    int* rowOff  = shiftA + 4096;      // [<=4097]
    int* phS     = rowOff + 4097;      // [nIn+nOut]
    int* phLen   = phS + (nIn + nOut); // [nIn+nOut]
    int* inRowA  = phLen + (nIn + nOut);
    int* inCol0  = inRowA + nIn;
    int* outRowA = inCol0 + nIn;
    int* outCol0 = outRowA + nOut;

    float* out = (float*)d_out;

    hipLaunchKernelGGL(k1_setup, dim3(1), dim3(64), 0, stream,
        ids, in_starts, out_starts, pM, BM, BS, inRows, outRows, nIn, nOut,
        shiftA, rowOff, phS, phLen, inRowA, inCol0, outRowA, outCol0);

    hipLaunchKernelGGL(k2_text, dim3((BS + 255) / 256), dim3(256), 0, stream,
        ids, attm, labels, pM, BM, BS, shiftA, rowOff, phS, phLen, map, out, D);

    const int ar = inRows + outRows;
    hipLaunchKernelGGL(k2_audio, dim3((ar + 255) / 256), dim3(256), 0, stream,
        in_starts, out_starts, pM, BM, BS, inRows, outRows, nIn, nOut,
        inRowA, inCol0, outRowA, outCol0, map, out, D);

    hipLaunchKernelGGL(k2_pad, dim3((BM + 255) / 256), dim3(256), 0, stream,
        pM, BM, shiftA, map, out, D);

    hipLaunchKernelGGL(k3_pos, dim3(16), dim3(256), 0, stream, pM, BM, out, D);

    hipLaunchKernelGGL(k4_copy, dim3(BM), dim3(256), 0, stream,
        audio_in, audio_out, inputs_embeds, pM, BM, BS, inRows, D, map, out);
}

// Round 2
// 479.812 us; speedup vs baseline: 2.2054x; 2.2054x over previous
//
#include <hip/hip_runtime.h>
#include <cstddef>

#define IN_IDX_C  128011
#define OUT_IDX_C 128012
#define PAD_ID_C  128001
#define IGNORE_C  (-100)

// ---------------------------------------------------------------------------
// kA_counts: 1 block, 1024 threads. Coalesced grid-stride over ids; per-row
// in/out placeholder counts via LDS atomics; thread 0 prefix-sums to global
// ordinal bases oin/oou (row-major global ordinals, matching jnp.nonzero).
// ---------------------------------------------------------------------------
__global__ void kA_counts(const int* __restrict__ ids,
                          const int* __restrict__ pM,
                          int BM, int BS,
                          int* __restrict__ oin, int* __restrict__ oou)
{
    const int M = pM[0];
    const int B = BM / M;
    const int S = BS / B;
    __shared__ int cin[1024], cou[1024];
    for (int b = threadIdx.x; b < B; b += blockDim.x) { cin[b] = 0; cou[b] = 0; }
    __syncthreads();
    for (int i = threadIdx.x; i < BS; i += blockDim.x) {
        const int v = ids[i];
        if (v == IN_IDX_C)       atomicAdd(&cin[i / S], 1);
        else if (v == OUT_IDX_C) atomicAdd(&cou[i / S], 1);
    }
    __syncthreads();
    if (threadIdx.x == 0) {
        int oi = 0, oo = 0;
        for (int b = 0; b < B; ++b) {
            oin[b] = oi; oou[b] = oo;
            oi += cin[b]; oo += cou[b];
        }
    }
}

// ---------------------------------------------------------------------------
// kB_row: one block per batch row (overprovisioned grid; device bounds check).
// 256 threads, each owning a contiguous chunk of S/256 source tokens.
// Walk 1 + scan: placeholder ordinals.  Walk 2 + scan: expansion (tpn) and
// attention-contribution cumsums.  Walk 3: write text metadata (incl.
// position_ids), map entries, and per-placeholder (row, startCol, posBase).
// ---------------------------------------------------------------------------
__global__ void kB_row(
    const int* __restrict__ ids, const int* __restrict__ attm,
    const int* __restrict__ labels,
    const int* __restrict__ in_starts, const int* __restrict__ out_starts,
    const int* __restrict__ pM, int BM, int BS,
    int inRows, int outRows, int nIn, int nOut,
    const int* __restrict__ oin, const int* __restrict__ oou,
    int* __restrict__ shiftA,
    int* __restrict__ inRowA, int* __restrict__ inCol0, int* __restrict__ inPos0,
    int* __restrict__ outRowA, int* __restrict__ outCol0, int* __restrict__ outPos0,
    int* __restrict__ map, float* __restrict__ out, int D)
{
    const int M = pM[0];
    const int B = BM / M;
    const int S = BS / B;
    const int b = blockIdx.x;
    if (b >= B) return;

    const int tid = threadIdx.x;
    const int T = blockDim.x;                  // 256
    const int CH = (S + T - 1) / T;
    const int s0 = tid * CH;
    const int s1 = (s0 + CH < S) ? (s0 + CH) : S;
    const int* row = ids + (size_t)b * S;

    __shared__ int sci[256], sco[256], stp[256], sat[256];

    // ---- walk 1: per-thread placeholder counts ----
    int ci = 0, co = 0;
    for (int s = s0; s < s1; ++s) {
        const int v = row[s];
        ci += (v == IN_IDX_C);
        co += (v == OUT_IDX_C);
    }
    sci[tid] = ci; sco[tid] = co;
    __syncthreads();
    for (int off = 1; off < T; off <<= 1) {
        int a = 0, c = 0;
        if (tid >= off) { a = sci[tid - off]; c = sco[tid - off]; }
        __syncthreads();
        sci[tid] += a; sco[tid] += c;
        __syncthreads();
    }
    const int eci = sci[tid] - ci;             // exclusive within-row ordinal base
    const int eco = sco[tid] - co;

    // ---- walk 2: expansion + attention contributions ----
    int pin = oin[b] + eci, pou = oou[b] + eco;
    int tp = 0, at = 0;
    for (int s = s0; s < s1; ++s) {
        const int v = row[s];
        if (v == IN_IDX_C) {
            const int st = in_starts[pin];
            const int en = (pin + 1 < nIn) ? in_starts[pin + 1] : inRows;
            tp += en - st; at += en - st; ++pin;
        } else if (v == OUT_IDX_C) {
            const int st = out_starts[pou];
            const int en = (pou + 1 < nOut) ? out_starts[pou + 1] : outRows;
            tp += en - st; at += en - st; ++pou;
        } else {
            tp += 1;
            at += attm[(size_t)b * S + s];
        }
    }
    stp[tid] = tp; sat[tid] = at;
    __syncthreads();
    for (int off = 1; off < T; off <<= 1) {
        int a = 0, c = 0;
        if (tid >= off) { a = stp[tid - off]; c = sat[tid - off]; }
        __syncthreads();
        stp[tid] += a; sat[tid] += c;
        __syncthreads();
    }
    const int total = stp[T - 1];
    const int shift = M - total;
    if (tid == 0) shiftA[b] = shift;

    // ---- walk 3: emit ----
    int col  = shift + (stp[tid] - tp);        // merged column cursor
    int acum = sat[tid] - at;                  // exclusive attention cumsum
    pin = oin[b] + eci; pou = oou[b] + eco;
    float* meta = out + (size_t)BM * D;
    for (int s = s0; s < s1; ++s) {
        const int v = row[s];
        if (v == IN_IDX_C) {
            const int st = in_starts[pin];
            const int en = (pin + 1 < nIn) ? in_starts[pin + 1] : inRows;
            const int len = en - st;
            inRowA[pin] = b; inCol0[pin] = col; inPos0[pin] = acum;
            col += len; acum += len; ++pin;
        } else if (v == OUT_IDX_C) {
            const int st = out_starts[pou];
            const int en = (pou + 1 < nOut) ? out_starts[pou + 1] : outRows;
            const int len = en - st;
            outRowA[pou] = b; outCol0[pou] = col; outPos0[pou] = acum;
            col += len; acum += len; ++pou;
        } else {
            const int a   = attm[(size_t)b * S + s];
            const int lab = labels[(size_t)b * S + s];
            const size_t idx = (size_t)b * M + col;
            map[idx] = s;
            meta[idx]                  = (float)a;
            meta[(size_t)BM     + idx] = (float)lab;
            meta[(size_t)BM * 2 + idx] = (a == 0) ? 1.f : (float)(acum + a - 1);
            meta[(size_t)BM * 3 + idx] = (float)v;
            meta[(size_t)BM * 4 + idx] = 0.f;
            meta[(size_t)BM * 5 + idx] = 0.f;
            meta[(size_t)BM * 6 + idx] = 0.f;
            col += 1; acum += a;
        }
    }
}

// ---------------------------------------------------------------------------
// k2_audio: one thread per audio embedding row; binary search placeholder,
// write map + metadata incl. position (posBase + local index).
// ---------------------------------------------------------------------------
__global__ void k2_audio(
    const int* __restrict__ in_starts, const int* __restrict__ out_starts,
    const int* __restrict__ pM, int BM, int BS, int inRows, int outRows,
    int nIn, int nOut,
    const int* __restrict__ inRowA, const int* __restrict__ inCol0,
    const int* __restrict__ inPos0,
    const int* __restrict__ outRowA, const int* __restrict__ outCol0,
    const int* __restrict__ outPos0,
    int* __restrict__ map, float* __restrict__ out, int D)
{
    int r = blockIdx.x * blockDim.x + threadIdx.x;
    if (r >= inRows + outRows) return;
    const int M = pM[0];
    const int B = BM / M;
    const int S = BS / B;
    int b, col, enc, iidv, infl, outfl, pos;
    if (r < inRows) {
        int lo = 0, hi = nIn - 1;
        while (lo < hi) { int mid = (lo + hi + 1) >> 1;
                          if (in_starts[mid] <= r) lo = mid; else hi = mid - 1; }
        const int j = r - in_starts[lo];
        b = inRowA[lo]; col = inCol0[lo] + j; pos = inPos0[lo] + j;
        enc = S + r; iidv = IN_IDX_C; infl = 1; outfl = 0;
    } else {
        const int r2 = r - inRows;
        int lo = 0, hi = nOut - 1;
        while (lo < hi) { int mid = (lo + hi + 1) >> 1;
                          if (out_starts[mid] <= r2) lo = mid; else hi = mid - 1; }
        const int j = r2 - out_starts[lo];
        b = outRowA[lo]; col = outCol0[lo] + j; pos = outPos0[lo] + j;
        enc = S + inRows + r2; iidv = OUT_IDX_C; infl = 0; outfl = 1;
    }
    const size_t idx = (size_t)b * M + col;
    map[idx] = enc;
    float* meta = out + (size_t)BM * D;
    meta[idx]                  = 1.f;
    meta[(size_t)BM     + idx] = (float)IGNORE_C;
    meta[(size_t)BM * 2 + idx] = (float)pos;
    meta[(size_t)BM * 3 + idx] = (float)iidv;
    meta[(size_t)BM * 4 + idx] = (float)infl;
    meta[(size_t)BM * 5 + idx] = (float)infl;
    meta[(size_t)BM * 6 + idx] = (float)outfl;
}

// ---------------------------------------------------------------------------
// k2_pad: one thread per merged column; only the left-pad region writes.
// ---------------------------------------------------------------------------
__global__ void k2_pad(
    const int* __restrict__ pM, int BM,
    const int* __restrict__ shiftA,
    int* __restrict__ map, float* __restrict__ out, int D)
{
    int i = blockIdx.x * blockDim.x + threadIdx.x;
    if (i >= BM) return;
    const int M = pM[0];
    const int b = i / M, m = i - b * M;
    if (m >= shiftA[b]) return;
    map[i] = -1;
    float* meta = out + (size_t)BM * D;
    meta[i]                  = 0.f;
    meta[(size_t)BM     + i] = (float)IGNORE_C;
    meta[(size_t)BM * 2 + i] = 1.f;            // pad position
    meta[(size_t)BM * 3 + i] = (float)PAD_ID_C;
    meta[(size_t)BM * 4 + i] = 0.f;
    meta[(size_t)BM * 5 + i] = 0.f;
    meta[(size_t)BM * 6 + i] = 0.f;
}

// ---------------------------------------------------------------------------
// k4_copy: one block per merged column; float4 gather-copy of D floats.
// Carries ~536 MB of the ~540 MB total traffic.
// ---------------------------------------------------------------------------
__global__ void k4_copy(
    const float* __restrict__ audio_in, const float* __restrict__ audio_out,
    const float* __restrict__ inputs_embeds, const int* __restrict__ pM,
    int BM, int BS, int inRows, int D,
    const int* __restrict__ map, float* __restrict__ out)
{
    const int bm = blockIdx.x;
    const int v = map[bm];
    float4* dst = (float4*)(out + (size_t)bm * D);
    const int nq = D >> 2;
    if (v < 0) {
        const float4 z = make_float4(0.f, 0.f, 0.f, 0.f);
        for (int i = threadIdx.x; i < nq; i += blockDim.x) dst[i] = z;
        return;
    }
    const int M = pM[0];
    const int B = BM / M;
    const int S = BS / B;
    const float* src;
    if (v < S) {
        const int b = bm / M;
        src = inputs_embeds + ((size_t)b * S + v) * (size_t)D;
    } else if (v < S + inRows) {
        src = audio_in + (size_t)(v - S) * D;
    } else {
        src = audio_out + (size_t)(v - S - inRows) * D;
    }
    const float4* s4 = (const float4*)src;
    for (int i = threadIdx.x; i < nq; i += blockDim.x) dst[i] = s4[i];
}

// ---------------------------------------------------------------------------
extern "C" void kernel_launch(void* const* d_in, const int* in_sizes, int n_inputs,
                              void* d_out, int out_size, void* d_ws, size_t ws_size,
                              hipStream_t stream) {
    (void)n_inputs; (void)ws_size;
    const float* audio_in      = (const float*)d_in[0];
    const float* audio_out     = (const float*)d_in[1];
    const float* inputs_embeds = (const float*)d_in[2];
    const int* in_starts  = (const int*)d_in[3];
    const int* out_starts = (const int*)d_in[4];
    const int* ids        = (const int*)d_in[5];
    const int* attm       = (const int*)d_in[6];
    const int* labels     = (const int*)d_in[7];
    const int* pM         = (const int*)d_in[8];   // max_token_num (device scalar)

    const int nIn     = in_sizes[3];
    const int nOut    = in_sizes[4];
    const int BS      = in_sizes[5];               // B*S
    const int D       = in_sizes[2] / BS;          // embed dim
    const int inRows  = in_sizes[0] / D;
    const int outRows = in_sizes[1] / D;
    const int BM      = out_size / (D + 7);        // B*M

    // workspace layout (ints)
    int* wsI     = (int*)d_ws;
    int* map     = wsI;                 // [BM]
    int* shiftA  = map + BM;            // [<=2048]
    int* oin     = shiftA + 2048;       // [<=2048]
    int* oou     = oin + 2048;          // [<=2048]
    int* inRowA  = oou + 2048;          // [nIn]
    int* inCol0  = inRowA + nIn;
    int* inPos0  = inCol0 + nIn;
    int* outRowA = inPos0 + nIn;        // [nOut]
    int* outCol0 = outRowA + nOut;
    int* outPos0 = outCol0 + nOut;

    float* out = (float*)d_out;

    hipLaunchKernelGGL(kA_counts, dim3(1), dim3(1024), 0, stream,
        ids, pM, BM, BS, oin, oou);

    // B unknown on host (M is a device scalar): overprovision, bounds-check.
    hipLaunchKernelGGL(kB_row, dim3(2048), dim3(256), 0, stream,
        ids, attm, labels, in_starts, out_starts, pM, BM, BS,
        inRows, outRows, nIn, nOut, oin, oou,
        shiftA, inRowA, inCol0, inPos0, outRowA, outCol0, outPos0,
        map, out, D);

    const int ar = inRows + outRows;
    hipLaunchKernelGGL(k2_audio, dim3((ar + 255) / 256), dim3(256), 0, stream,
        in_starts, out_starts, pM, BM, BS, inRows, outRows, nIn, nOut,
        inRowA, inCol0, inPos0, outRowA, outCol0, outPos0, map, out, D);

    hipLaunchKernelGGL(k2_pad, dim3((BM + 255) / 256), dim3(256), 0, stream,
        pM, BM, shiftA, map, out, D);

    hipLaunchKernelGGL(k4_copy, dim3(BM), dim3(256), 0, stream,
        audio_in, audio_out, inputs_embeds, pM, BM, BS, inRows, D, map, out);
}